// Round 7
// baseline (291.878 us; speedup 1.0000x reference)
//
#include <hip/hip_runtime.h>
#include <stdint.h>

#define N_V 50000
#define F_DIM 128
#define K_DIM 128
#define H_DIM 3
#define M_DIM 10

using bf16x8 = __attribute__((ext_vector_type(8))) short;  // 8 bf16 = 4 VGPRs
using f32x4  = __attribute__((ext_vector_type(4))) float;

__device__ inline unsigned short f2bf(float f) {
    union { float f; uint32_t u; } v; v.f = f;
    uint32_t u = v.u;
    u += 0x7fffu + ((u >> 16) & 1u);   // round-to-nearest-even
    return (unsigned short)(u >> 16);
}

#define LDS_AS __attribute__((address_space(3)))
__device__ inline void gl2lds16(const void* g, void* l) {
    __builtin_amdgcn_global_load_lds(
        (const __attribute__((address_space(1))) unsigned int*)g,
        (LDS_AS unsigned int*)l, 16, 0, 0);
}

// ---------------------------------------------------------------------------
// Kernel 1 (prep): a) W (H,F,K) fp32 -> Wt[b][k][f] bf16; b) X -> Xb bf16;
// c) wa[b][f] = W_b[f,:] . a_vec_b  -> bf16 (for e = X*wa via MFMA)
// ---------------------------------------------------------------------------
#define WTOT (9 * 128 * 128)
#define XCH  (N_V * 16)
#define WACT (9 * 128)

__global__ void prep(const float* __restrict__ Wvc,
                     const float* __restrict__ Wvn_int,
                     const float* __restrict__ Wvn_nh,
                     const float* __restrict__ X,
                     const float* __restrict__ a,
                     unsigned short* __restrict__ Wt,
                     unsigned short* __restrict__ Xb,
                     unsigned short* __restrict__ wab) {
    int idx = blockIdx.x * 256 + threadIdx.x;
    if (idx < WTOT) {
        int b   = idx >> 14;
        int rem = idx & 16383;
        int k = rem >> 7;
        int f = rem & 127;
        int h = b / 3, t = b - 3 * h;
        const float* src = (t == 0) ? Wvc : (t == 1) ? Wvn_int : Wvn_nh;
        Wt[idx] = f2bf(src[(h * 128 + f) * 128 + k]);
        return;
    }
    int xi = idx - WTOT;
    if (xi < XCH) {
        const float4* Xv = (const float4*)X;
        float4 v0 = Xv[xi * 2];
        float4 v1 = Xv[xi * 2 + 1];
        uint4 o;
        o.x = (uint32_t)f2bf(v0.x) | ((uint32_t)f2bf(v0.y) << 16);
        o.y = (uint32_t)f2bf(v0.z) | ((uint32_t)f2bf(v0.w) << 16);
        o.z = (uint32_t)f2bf(v1.x) | ((uint32_t)f2bf(v1.y) << 16);
        o.w = (uint32_t)f2bf(v1.z) | ((uint32_t)f2bf(v1.w) << 16);
        *(uint4*)&Xb[(size_t)xi * 8] = o;
        return;
    }
    int wi = xi - XCH;
    if (wi < WACT) {
        int b = wi >> 7, f = wi & 127;
        int h = b / 3, t = b - 3 * h;
        const float* src = (t == 0) ? Wvc : (t == 1) ? Wvn_int : Wvn_nh;
        const float4* wrow = (const float4*)&src[(h * 128 + f) * 128];
        const float4* av   = (const float4*)&a[h * 256 + (t == 0 ? 128 : 0)];
        float acc = 0.f;
        #pragma unroll 8
        for (int c = 0; c < 32; ++c) {
            float4 w = wrow[c], x = av[c];
            acc += w.x * x.x + w.y * x.y + w.z * x.z + w.w * x.w;
        }
        wab[b * 128 + f] = f2bf(acc);
    }
}

// ---------------------------------------------------------------------------
// Kernel 2: MFMA GEMM (R4 structure). Grid = (ceil(N/64), 9), 4 waves.
// NEW: V stored head-interleaved V[j][h*128+col]; e stored e[j*3+h].
// Zc -> out fp32 (out is already the [n][h*128+col] layout).
// ---------------------------------------------------------------------------
__global__ __launch_bounds__(256, 3) void gemm_kernel(
    const unsigned short* __restrict__ Xb,  // N_V x 128 bf16
    const unsigned short* __restrict__ Wt,  // 9 x 128(k) x 128(f) bf16
    const unsigned short* __restrict__ wab, // 9 x 128 bf16
    float* __restrict__ out,                // N_V x 384
    unsigned short* __restrict__ Vint,      // N_V x 384 bf16 (head-interleaved)
    unsigned short* __restrict__ Vnh,       // N_V x 384 bf16
    float* __restrict__ ecall,              // N_V x 3
    float* __restrict__ eiall,
    float* __restrict__ enall) {
    __shared__ unsigned short As[64 * 128];   // 16 KB, swizzled

    const int tid    = threadIdx.x;
    const int b      = blockIdx.y;
    const int h      = b / 3;
    const int t      = b - 3 * h;
    const int m_base = blockIdx.x * 64;
    const int wv     = tid >> 6;
    const int lane   = tid & 63;
    const int q      = lane >> 4;
    const int ln     = lane & 15;

    // ---- B fragments (direct global, L2-hot). col = wv*32 + 2*ln + ct.
    const unsigned short* Wb = Wt + b * 16384;
    bf16x8 bfr[2][4];
    #pragma unroll
    for (int ct = 0; ct < 2; ++ct) {
        int col = wv * 32 + 2 * ln + ct;
        #pragma unroll
        for (int kk = 0; kk < 4; ++kk)
            bfr[ct][kk] = *(const bf16x8*)&Wb[col * 128 + kk * 32 + q * 8];
    }

    // ---- A staging: 1024 chunks of 16B, XOR-16 swizzle, wave-uniform dest.
    #pragma unroll
    for (int it = 0; it < 4; ++it) {
        int c16 = it * 256 + tid;
        int r   = c16 >> 4;
        int p   = c16 & 15;
        int lch = p ^ (r & 15);
        int gr  = m_base + r;
        if (gr >= N_V) gr = 0;
        gl2lds16(Xb + (size_t)gr * 128 + lch * 8, &As[c16 * 8]);
    }
    __syncthreads();

    // ---- main MFMA
    f32x4 acc[4][2];
    #pragma unroll
    for (int rt = 0; rt < 4; ++rt)
        #pragma unroll
        for (int ct = 0; ct < 2; ++ct) acc[rt][ct] = (f32x4){0.f, 0.f, 0.f, 0.f};

    #pragma unroll
    for (int rt = 0; rt < 4; ++rt) {
        int r = rt * 16 + ln;
        #pragma unroll
        for (int kk = 0; kk < 4; ++kk) {
            int p = (kk * 4 + q) ^ ln;
            bf16x8 afr = *(const bf16x8*)&As[r * 128 + p * 8];
            acc[rt][0] = __builtin_amdgcn_mfma_f32_16x16x32_bf16(afr, bfr[0][kk], acc[rt][0], 0, 0, 0);
            acc[rt][1] = __builtin_amdgcn_mfma_f32_16x16x32_bf16(afr, bfr[1][kk], acc[rt][1], 0, 0, 0);
        }
    }

    // ---- e = A * wa  (wave 0 only; B col 0 = wa). e layout: e[j*3+h].
    if (wv == 0) {
        bf16x8 wz[4];
        #pragma unroll
        for (int kk = 0; kk < 4; ++kk) {
            bf16x8 z = {0, 0, 0, 0, 0, 0, 0, 0};
            if (ln == 0) z = *(const bf16x8*)&wab[b * 128 + kk * 32 + q * 8];
            wz[kk] = z;
        }
        float* e_arr = (t == 0) ? ecall : (t == 1) ? eiall : enall;
        #pragma unroll
        for (int rt = 0; rt < 4; ++rt) {
            int r = rt * 16 + ln;
            f32x4 ae = (f32x4){0.f, 0.f, 0.f, 0.f};
            #pragma unroll
            for (int kk = 0; kk < 4; ++kk) {
                int p = (kk * 4 + q) ^ ln;
                bf16x8 afr = *(const bf16x8*)&As[r * 128 + p * 8];
                ae = __builtin_amdgcn_mfma_f32_16x16x32_bf16(afr, wz[kk], ae, 0, 0, 0);
            }
            if (ln == 0) {
                #pragma unroll
                for (int rg = 0; rg < 4; ++rg) {
                    int gr = m_base + rt * 16 + q * 4 + rg;
                    if (gr < N_V) e_arr[gr * 3 + h] = ae[rg];
                }
            }
        }
    }

    // ---- stores: thread owns adjacent cols c0 = wv*32 + 2*ln, c0+1.
    const int c0 = wv * 32 + 2 * ln;
    if (t == 0) {
        #pragma unroll
        for (int rt = 0; rt < 4; ++rt)
            #pragma unroll
            for (int rg = 0; rg < 4; ++rg) {
                int gr = m_base + rt * 16 + q * 4 + rg;
                if (gr >= N_V) continue;
                float2 v = make_float2(acc[rt][0][rg], acc[rt][1][rg]);
                *(float2*)&out[(size_t)gr * 384 + h * 128 + c0] = v;
            }
    } else {
        unsigned short* Vside = (t == 1) ? Vint : Vnh;
        #pragma unroll
        for (int rt = 0; rt < 4; ++rt)
            #pragma unroll
            for (int rg = 0; rg < 4; ++rg) {
                int gr = m_base + rt * 16 + q * 4 + rg;
                if (gr >= N_V) continue;
                uint32_t pk = (uint32_t)f2bf(acc[rt][0][rg]) |
                              ((uint32_t)f2bf(acc[rt][1][rg]) << 16);
                *(uint32_t*)&Vside[(size_t)gr * 384 + h * 128 + c0] = pk;
            }
    }
}

// ---------------------------------------------------------------------------
// Kernel 3: merged attention, ALL heads in one wave per vertex.
// Phase 1 (lanes 0..59, lane = h*20+br*10+m): logits from e[j*3+h]+ec[n*3+h],
// 10-lane shuffle softmax, alpha/(s*norm) folded.
// Phase 2: 20 gathers of head-interleaved V rows (768 B, lanes 0..47 x 16 B
// = ONE contiguous segment each); per-lane acc[8], no cross-lane reduce.
// Epilogue: lanes 0..47 RMW out (Zc slice) + bv, ReLU.
// ---------------------------------------------------------------------------
__global__ __launch_bounds__(256) void attn_kernel(
    const int* __restrict__ nh_idx, const int* __restrict__ int_idx,
    const float* __restrict__ nh_edge, const float* __restrict__ int_edge,
    const float* __restrict__ bv,
    const unsigned short* __restrict__ Vint, const unsigned short* __restrict__ Vnh,
    const float* __restrict__ ecall, const float* __restrict__ eiall,
    const float* __restrict__ enall,
    float* __restrict__ out) {
    const int wv   = threadIdx.x >> 6;
    const int lane = threadIdx.x & 63;
    const int n    = blockIdx.x * 4 + wv;
    if (n >= N_V) return;

    const bool act = (lane < 60);
    const int  h3  = lane / 20;            // 0..3 (3 only for lanes 60-63)
    const int  r   = lane - h3 * 20;
    const int  br  = r / 10;
    const int  m   = r - br * 10;
    const int  hcl = (h3 < 3) ? h3 : 2;

    int jm = -1; float wm = 0.f;
    if (act) {
        const int*   ia = br ? nh_idx  : int_idx;
        const float* ea = br ? nh_edge : int_edge;
        jm = ia[n * M_DIM + m];
        wm = ea[n * M_DIM + m];
    }
    const bool  valid = act && (jm >= 0);
    const int   jc    = valid ? jm : 0;
    const float vfl   = valid ? 1.f : 0.f;

    float logit = 0.f;
    if (act) {
        const float* es = br ? enall : eiall;
        float e  = es[jc * 3 + hcl];
        float ec = ecall[n * 3 + hcl];
        logit = valid ? (e + ec) * wm : 0.f;
    }

    // ---- softmax over the 10-lane (h,br) group
    const int g0 = (lane / 10) * 10;
    float mx = logit;
    #pragma unroll
    for (int k = 0; k < 10; ++k) mx = fmaxf(mx, __shfl(logit, g0 + k, 64));
    float ex = act ? __expf(logit - mx) : 0.f;
    float sv = 0.f, cf = 0.f;
    #pragma unroll
    for (int k = 0; k < 10; ++k) {
        sv += __shfl(ex,  g0 + k, 64);
        cf += __shfl(vfl, g0 + k, 64);
    }
    float alphap = valid ? ex / (sv * fmaxf(cf, 1.f)) : 0.f;

    // ---- gather phase: lane covers global cols [off, off+8), head = off>>7
    const int off  = ((lane < 48) ? lane : (lane - 16)) * 8;  // clamp tail lanes
    const int ab   = ((lane < 48) ? h3 : 2) * 20;             // alpha block base
    float acc[8] = {0.f, 0.f, 0.f, 0.f, 0.f, 0.f, 0.f, 0.f};
    #pragma unroll
    for (int b2 = 0; b2 < 2; ++b2) {
        const unsigned short* Vb = b2 ? Vnh : Vint;
        #pragma unroll
        for (int mm = 0; mm < M_DIM; ++mm) {
            int   j  = __shfl(jc, b2 * 10 + mm, 64);
            float al = __shfl(alphap, ab + b2 * 10 + mm, 64);
            uint4 pv = *(const uint4*)&Vb[(size_t)j * 384 + off];
            uint32_t w4[4] = {pv.x, pv.y, pv.z, pv.w};
            #pragma unroll
            for (int c = 0; c < 4; ++c) {
                union { uint32_t u; float f; } lo, hi;
                lo.u = w4[c] << 16;
                hi.u = w4[c] & 0xffff0000u;
                acc[2 * c]     += al * lo.f;
                acc[2 * c + 1] += al * hi.f;
            }
        }
    }

    // ---- epilogue: lanes 0..47 own cols [lane*8, lane*8+8)
    if (lane < 48) {
        size_t o = (size_t)n * 384 + lane * 8;
        float4 z0 = *(const float4*)&out[o];
        float4 z1 = *(const float4*)&out[o + 4];
        float4 b0 = *(const float4*)&bv[lane * 8];
        float4 b1 = *(const float4*)&bv[lane * 8 + 4];
        float4 r0, r1;
        r0.x = fmaxf(z0.x + acc[0] + b0.x, 0.f);
        r0.y = fmaxf(z0.y + acc[1] + b0.y, 0.f);
        r0.z = fmaxf(z0.z + acc[2] + b0.z, 0.f);
        r0.w = fmaxf(z0.w + acc[3] + b0.w, 0.f);
        r1.x = fmaxf(z1.x + acc[4] + b1.x, 0.f);
        r1.y = fmaxf(z1.y + acc[5] + b1.y, 0.f);
        r1.z = fmaxf(z1.z + acc[6] + b1.z, 0.f);
        r1.w = fmaxf(z1.w + acc[7] + b1.w, 0.f);
        *(float4*)&out[o]     = r0;
        *(float4*)&out[o + 4] = r1;
    }
}

// ---------------------------------------------------------------------------
extern "C" void kernel_launch(void* const* d_in, const int* in_sizes, int n_in,
                              void* d_out, int out_size, void* d_ws, size_t ws_size,
                              hipStream_t stream) {
    const float* vertices    = (const float*)d_in[0];
    const int*   nh_indices  = (const int*)d_in[1];
    const int*   int_indices = (const int*)d_in[2];
    const float* nh_edges    = (const float*)d_in[3];
    const float* int_edges   = (const float*)d_in[4];
    // d_in[5] is_int: unused by the reference
    const float* Wvc     = (const float*)d_in[6];
    const float* bv      = (const float*)d_in[7];
    const float* Wvn_int = (const float*)d_in[8];
    const float* Wvn_nh  = (const float*)d_in[9];
    const float* a       = (const float*)d_in[10];
    float* out = (float*)d_out;

    char* ws = (char*)d_ws;
    size_t off = 0;
    unsigned short* Wt = (unsigned short*)(ws + off);
    off += (size_t)WTOT * 2;                  off = (off + 255) & ~(size_t)255;
    unsigned short* wab = (unsigned short*)(ws + off);
    off += (size_t)WACT * 2;                  off = (off + 255) & ~(size_t)255;
    unsigned short* Xb = (unsigned short*)(ws + off);
    off += (size_t)N_V * 128 * 2;             off = (off + 255) & ~(size_t)255;
    unsigned short* Vint = (unsigned short*)(ws + off);
    off += (size_t)N_V * 384 * 2 + 512;       off = (off + 255) & ~(size_t)255;
    unsigned short* Vnh = (unsigned short*)(ws + off);
    off += (size_t)N_V * 384 * 2 + 512;       off = (off + 255) & ~(size_t)255;
    float* ecall = (float*)(ws + off);
    off += (size_t)N_V * 3 * 4 + 256;         off = (off + 255) & ~(size_t)255;
    float* eiall = (float*)(ws + off);
    off += (size_t)N_V * 3 * 4 + 256;         off = (off + 255) & ~(size_t)255;
    float* enall = (float*)(ws + off);
    off += (size_t)N_V * 3 * 4 + 256;

    int prep_threads = WTOT + XCH + WACT;
    prep<<<(prep_threads + 255) / 256, 256, 0, stream>>>(
        Wvc, Wvn_int, Wvn_nh, vertices, a, Wt, Xb, wab);

    dim3 grid_g((N_V + 63) / 64, 9);
    gemm_kernel<<<grid_g, 256, 0, stream>>>(Xb, Wt, wab, out, Vint, Vnh,
                                            ecall, eiall, enall);

    attn_kernel<<<(N_V + 3) / 4, 256, 0, stream>>>(nh_indices, int_indices,
                                                   nh_edges, int_edges, bv,
                                                   Vint, Vnh, ecall, eiall,
                                                   enall, out);
}

// Round 8
// 260.554 us; speedup vs baseline: 1.1202x; 1.1202x over previous
//
#include <hip/hip_runtime.h>
#include <stdint.h>

#define N_V 50000
#define F_DIM 128
#define K_DIM 128
#define H_DIM 3
#define M_DIM 10

using bf16x8 = __attribute__((ext_vector_type(8))) short;  // 8 bf16 = 4 VGPRs
using f32x4  = __attribute__((ext_vector_type(4))) float;

__device__ inline unsigned short f2bf(float f) {
    union { float f; uint32_t u; } v; v.f = f;
    uint32_t u = v.u;
    u += 0x7fffu + ((u >> 16) & 1u);   // round-to-nearest-even
    return (unsigned short)(u >> 16);
}

#define LDS_AS __attribute__((address_space(3)))
__device__ inline void gl2lds16(const void* g, void* l) {
    __builtin_amdgcn_global_load_lds(
        (const __attribute__((address_space(1))) unsigned int*)g,
        (LDS_AS unsigned int*)l, 16, 0, 0);
}

// ---------------------------------------------------------------------------
// Kernel 1 (prep): a) W (H,F,K) fp32 -> Wt[b][k][f] bf16; b) X -> Xb bf16;
// c) wa[b][f] = W_b[f,:] . a_vec_b  -> bf16 (for e = X*wa via MFMA)
// ---------------------------------------------------------------------------
#define WTOT (9 * 128 * 128)
#define XCH  (N_V * 16)
#define WACT (9 * 128)

__global__ void prep(const float* __restrict__ Wvc,
                     const float* __restrict__ Wvn_int,
                     const float* __restrict__ Wvn_nh,
                     const float* __restrict__ X,
                     const float* __restrict__ a,
                     unsigned short* __restrict__ Wt,
                     unsigned short* __restrict__ Xb,
                     unsigned short* __restrict__ wab) {
    int idx = blockIdx.x * 256 + threadIdx.x;
    if (idx < WTOT) {
        int b   = idx >> 14;
        int rem = idx & 16383;
        int k = rem >> 7;
        int f = rem & 127;
        int h = b / 3, t = b - 3 * h;
        const float* src = (t == 0) ? Wvc : (t == 1) ? Wvn_int : Wvn_nh;
        Wt[idx] = f2bf(src[(h * 128 + f) * 128 + k]);
        return;
    }
    int xi = idx - WTOT;
    if (xi < XCH) {
        const float4* Xv = (const float4*)X;
        float4 v0 = Xv[xi * 2];
        float4 v1 = Xv[xi * 2 + 1];
        uint4 o;
        o.x = (uint32_t)f2bf(v0.x) | ((uint32_t)f2bf(v0.y) << 16);
        o.y = (uint32_t)f2bf(v0.z) | ((uint32_t)f2bf(v0.w) << 16);
        o.z = (uint32_t)f2bf(v1.x) | ((uint32_t)f2bf(v1.y) << 16);
        o.w = (uint32_t)f2bf(v1.z) | ((uint32_t)f2bf(v1.w) << 16);
        *(uint4*)&Xb[(size_t)xi * 8] = o;
        return;
    }
    int wi = xi - XCH;
    if (wi < WACT) {
        int b = wi >> 7, f = wi & 127;
        int h = b / 3, t = b - 3 * h;
        const float* src = (t == 0) ? Wvc : (t == 1) ? Wvn_int : Wvn_nh;
        const float4* wrow = (const float4*)&src[(h * 128 + f) * 128];
        const float4* av   = (const float4*)&a[h * 256 + (t == 0 ? 128 : 0)];
        float acc = 0.f;
        #pragma unroll 8
        for (int c = 0; c < 32; ++c) {
            float4 w = wrow[c], x = av[c];
            acc += w.x * x.x + w.y * x.y + w.z * x.z + w.w * x.w;
        }
        wab[b * 128 + f] = f2bf(acc);
    }
}

// ---------------------------------------------------------------------------
// Kernel 2: MFMA GEMM. Grid = (ceil(N/64), 9), 4 waves.
// Tiling: wave pair (wv>>1) owns a 64-col half; (wv&1) owns a 32-row half.
// B-tile ct holds cols {cb + 4*ln + ct} so each thread owns 4 ADJACENT cols:
//   t==0 -> Zc float4 stores; t==1/2 -> V fp8 e4m3 dword stores (4 packed).
// e = A*wa via MFMA on waves 0,1 (rows 0-31 / 32-63).
// ---------------------------------------------------------------------------
__global__ __launch_bounds__(256, 3) void gemm_kernel(
    const unsigned short* __restrict__ Xb,  // N_V x 128 bf16
    const unsigned short* __restrict__ Wt,  // 9 x 128(k) x 128(f) bf16
    const unsigned short* __restrict__ wab, // 9 x 128 bf16
    float* __restrict__ out,                // N_V x 384
    uint8_t* __restrict__ Vint,             // H x N_V x 128 fp8
    uint8_t* __restrict__ Vnh,              // H x N_V x 128 fp8
    float* __restrict__ e_center,           // H*N_V
    float* __restrict__ e_int,
    float* __restrict__ e_nh) {
    __shared__ unsigned short As[64 * 128];   // 16 KB, swizzled

    const int tid    = threadIdx.x;
    const int b      = blockIdx.y;
    const int h      = b / 3;
    const int t      = b - 3 * h;
    const int m_base = blockIdx.x * 64;
    const int wv     = tid >> 6;
    const int lane   = tid & 63;
    const int q      = lane >> 4;
    const int ln     = lane & 15;
    const int cb     = (wv >> 1) * 64;   // column half base
    const int rb     = (wv & 1) * 32;    // row half base

    // ---- B fragments (direct global, L2-hot). tile ct: col = cb + 4*ln + ct
    const unsigned short* Wb = Wt + b * 16384;
    bf16x8 bfr[4][4];
    #pragma unroll
    for (int ct = 0; ct < 4; ++ct) {
        int col = cb + 4 * ln + ct;
        #pragma unroll
        for (int kk = 0; kk < 4; ++kk)
            bfr[ct][kk] = *(const bf16x8*)&Wb[col * 128 + kk * 32 + q * 8];
    }

    // ---- A staging: 1024 chunks of 16B, XOR-16 swizzle, wave-uniform dest.
    #pragma unroll
    for (int it = 0; it < 4; ++it) {
        int c16 = it * 256 + tid;
        int r   = c16 >> 4;
        int p   = c16 & 15;
        int lch = p ^ (r & 15);
        int gr  = m_base + r;
        if (gr >= N_V) gr = 0;
        gl2lds16(Xb + (size_t)gr * 128 + lch * 8, &As[c16 * 8]);
    }
    __syncthreads();

    // ---- A fragments for this wave's 32-row half
    bf16x8 afr[2][4];
    #pragma unroll
    for (int rt = 0; rt < 2; ++rt) {
        int r = rb + rt * 16 + ln;
        #pragma unroll
        for (int kk = 0; kk < 4; ++kk) {
            int p = (kk * 4 + q) ^ ln;   // unswizzle (r & 15 == ln)
            afr[rt][kk] = *(const bf16x8*)&As[r * 128 + p * 8];
        }
    }

    // ---- main MFMA: 2 row-tiles x 4 col-tiles x 4 k-steps = 32 MFMA
    f32x4 acc[2][4];
    #pragma unroll
    for (int rt = 0; rt < 2; ++rt)
        #pragma unroll
        for (int ct = 0; ct < 4; ++ct) acc[rt][ct] = (f32x4){0.f, 0.f, 0.f, 0.f};

    #pragma unroll
    for (int rt = 0; rt < 2; ++rt)
        #pragma unroll
        for (int kk = 0; kk < 4; ++kk)
            #pragma unroll
            for (int ct = 0; ct < 4; ++ct)
                acc[rt][ct] = __builtin_amdgcn_mfma_f32_16x16x32_bf16(
                    afr[rt][kk], bfr[ct][kk], acc[rt][ct], 0, 0, 0);

    // ---- e = A * wa  (waves 0,1 cover rows 0-31 / 32-63; B col 0 = wa)
    if (wv < 2) {
        bf16x8 wz[4];
        #pragma unroll
        for (int kk = 0; kk < 4; ++kk) {
            bf16x8 z = {0, 0, 0, 0, 0, 0, 0, 0};
            if (ln == 0) z = *(const bf16x8*)&wab[b * 128 + kk * 32 + q * 8];
            wz[kk] = z;
        }
        float* e_arr = (t == 0) ? e_center : (t == 1) ? e_int : e_nh;
        #pragma unroll
        for (int rt = 0; rt < 2; ++rt) {
            f32x4 ae = (f32x4){0.f, 0.f, 0.f, 0.f};
            #pragma unroll
            for (int kk = 0; kk < 4; ++kk)
                ae = __builtin_amdgcn_mfma_f32_16x16x32_bf16(afr[rt][kk], wz[kk], ae, 0, 0, 0);
            if (ln == 0) {
                #pragma unroll
                for (int rg = 0; rg < 4; ++rg) {
                    int gr = m_base + rb + rt * 16 + q * 4 + rg;
                    if (gr < N_V) e_arr[h * N_V + gr] = ae[rg];
                }
            }
        }
    }

    // ---- stores: thread owns 4 adjacent cols c0 = cb + 4*ln .. +3
    const int c0 = cb + 4 * ln;
    if (t == 0) {
        #pragma unroll
        for (int rt = 0; rt < 2; ++rt)
            #pragma unroll
            for (int rg = 0; rg < 4; ++rg) {
                int gr = m_base + rb + rt * 16 + q * 4 + rg;
                if (gr >= N_V) continue;
                float4 v = make_float4(acc[rt][0][rg], acc[rt][1][rg],
                                       acc[rt][2][rg], acc[rt][3][rg]);
                *(float4*)&out[(size_t)gr * 384 + h * 128 + c0] = v;
            }
    } else {
        uint8_t* Vside = (t == 1) ? Vint : Vnh;
        #pragma unroll
        for (int rt = 0; rt < 2; ++rt)
            #pragma unroll
            for (int rg = 0; rg < 4; ++rg) {
                int gr = m_base + rb + rt * 16 + q * 4 + rg;
                if (gr >= N_V) continue;
                int pk = __builtin_amdgcn_cvt_pk_fp8_f32(
                    acc[rt][0][rg], acc[rt][1][rg], 0, false);
                pk = __builtin_amdgcn_cvt_pk_fp8_f32(
                    acc[rt][2][rg], acc[rt][3][rg], pk, true);
                *(uint32_t*)&Vside[((size_t)(h * N_V + gr)) * 128 + c0] =
                    (uint32_t)pk;
            }
    }
}

// ---------------------------------------------------------------------------
// Kernel 3: attention for ONE head (R6 structure, V now fp8 e4m3, 128 B/row).
// One wave per vertex, 4 groups x 16 lanes; group gathers a full row via
// dwordx2 (8 fp8/lane); HW cvt_pk_f32_fp8 unpack; folded alpha/norm;
// xor-16/32 cross-group reduce; fused bias+ReLU epilogue.
// ---------------------------------------------------------------------------
__global__ __launch_bounds__(256) void attn_head_kernel(
    const int* __restrict__ nh_idx, const int* __restrict__ int_idx,
    const float* __restrict__ nh_edge, const float* __restrict__ int_edge,
    const float* __restrict__ bv_h,
    const uint8_t* __restrict__ Vint_h,
    const uint8_t* __restrict__ Vnh_h,
    const float* __restrict__ ec_h, const float* __restrict__ ei_h,
    const float* __restrict__ en_h,
    float* __restrict__ out, int hoff) {
    const int wv   = threadIdx.x >> 6;
    const int lane = threadIdx.x & 63;
    const int n    = blockIdx.x * 4 + wv;
    if (n >= N_V) return;
    const int g  = lane >> 4;
    const int gl = lane & 15;

    const bool part = (g <= 1) && (gl < M_DIM);
    int jm = -1; float wm = 0.f;
    if (part) {
        const int*   idx = (g == 0) ? int_idx  : nh_idx;
        const float* ed  = (g == 0) ? int_edge : nh_edge;
        jm = idx[n * M_DIM + gl];
        wm = ed[n * M_DIM + gl];
    }
    const bool  valid = part && (jm >= 0);
    const int   jc    = valid ? jm : 0;
    const float vfl   = valid ? 1.f : 0.f;

    float ec = ec_h[n];

    // ---- logits (lanes 0-9: int, 16-25: nh). masked entries logit = 0.
    float l = -3.0e38f;
    if (part) {
        const float* es = (g == 0) ? ei_h : en_h;
        float e = es[jc];
        l = valid ? (e + ec) * wm : 0.f;
    }
    float mx = l;
    #pragma unroll
    for (int off = 1; off < 16; off <<= 1) mx = fmaxf(mx, __shfl_xor(mx, off, 64));
    float ex = part ? __expf(l - mx) : 0.f;
    float sv = ex, cf = vfl;
    #pragma unroll
    for (int off = 1; off < 16; off <<= 1) {
        sv += __shfl_xor(sv, off, 64);
        cf += __shfl_xor(cf, off, 64);
    }
    float alphap = 0.f;
    if (valid) alphap = ex / (sv * fmaxf(cf, 1.f));

    // ---- gather: group g handles 5 rows of its branch (128 B fp8 rows)
    const uint8_t* Vb = (g < 2) ? Vint_h : Vnh_h;
    const int src_base = (g < 2 ? 0 : 16) + (g & 1) * 5;
    float acc[8] = {0.f, 0.f, 0.f, 0.f, 0.f, 0.f, 0.f, 0.f};
    #pragma unroll
    for (int i = 0; i < 5; ++i) {
        int   src = src_base + i;
        int   j   = __shfl(jc, src, 64);
        float al  = __shfl(alphap, src, 64);
        uint2 pv  = *(const uint2*)&Vb[(size_t)j * 128 + gl * 8];
        auto f01 = __builtin_amdgcn_cvt_pk_f32_fp8(pv.x, false);
        auto f23 = __builtin_amdgcn_cvt_pk_f32_fp8(pv.x, true);
        auto f45 = __builtin_amdgcn_cvt_pk_f32_fp8(pv.y, false);
        auto f67 = __builtin_amdgcn_cvt_pk_f32_fp8(pv.y, true);
        acc[0] += al * f01[0];
        acc[1] += al * f01[1];
        acc[2] += al * f23[0];
        acc[3] += al * f23[1];
        acc[4] += al * f45[0];
        acc[5] += al * f45[1];
        acc[6] += al * f67[0];
        acc[7] += al * f67[1];
    }
    #pragma unroll
    for (int c = 0; c < 8; ++c) {
        acc[c] += __shfl_xor(acc[c], 16, 64);
        acc[c] += __shfl_xor(acc[c], 32, 64);
    }
    if (g < 2) {
        size_t o = (size_t)n * 384 + hoff + gl * 8 + g * 4;
        float4 zc = *(const float4*)&out[o];
        float4 bb = *(const float4*)&bv_h[gl * 8 + g * 4];
        float4 zn;
        if (g == 0) zn = make_float4(acc[0], acc[1], acc[2], acc[3]);
        else        zn = make_float4(acc[4], acc[5], acc[6], acc[7]);
        float4 r;
        r.x = fmaxf(zc.x + zn.x + bb.x, 0.f);
        r.y = fmaxf(zc.y + zn.y + bb.y, 0.f);
        r.z = fmaxf(zc.z + zn.z + bb.z, 0.f);
        r.w = fmaxf(zc.w + zn.w + bb.w, 0.f);
        *(float4*)&out[o] = r;
    }
}

// ---------------------------------------------------------------------------
extern "C" void kernel_launch(void* const* d_in, const int* in_sizes, int n_in,
                              void* d_out, int out_size, void* d_ws, size_t ws_size,
                              hipStream_t stream) {
    const float* vertices    = (const float*)d_in[0];
    const int*   nh_indices  = (const int*)d_in[1];
    const int*   int_indices = (const int*)d_in[2];
    const float* nh_edges    = (const float*)d_in[3];
    const float* int_edges   = (const float*)d_in[4];
    // d_in[5] is_int: unused by the reference
    const float* Wvc     = (const float*)d_in[6];
    const float* bv      = (const float*)d_in[7];
    const float* Wvn_int = (const float*)d_in[8];
    const float* Wvn_nh  = (const float*)d_in[9];
    const float* a       = (const float*)d_in[10];
    float* out = (float*)d_out;

    char* ws = (char*)d_ws;
    size_t off = 0;
    unsigned short* Wt = (unsigned short*)(ws + off);
    off += (size_t)WTOT * 2;                  off = (off + 255) & ~(size_t)255;
    unsigned short* wab = (unsigned short*)(ws + off);
    off += (size_t)WACT * 2;                  off = (off + 255) & ~(size_t)255;
    unsigned short* Xb = (unsigned short*)(ws + off);
    off += (size_t)N_V * 128 * 2;             off = (off + 255) & ~(size_t)255;
    uint8_t* Vint = (uint8_t*)(ws + off);
    off += (size_t)H_DIM * N_V * 128;         off = (off + 255) & ~(size_t)255;
    uint8_t* Vnh = (uint8_t*)(ws + off);
    off += (size_t)H_DIM * N_V * 128;         off = (off + 255) & ~(size_t)255;
    float* e_center = (float*)(ws + off);
    off += (size_t)H_DIM * N_V * 4;           off = (off + 255) & ~(size_t)255;
    float* e_int = (float*)(ws + off);
    off += (size_t)H_DIM * N_V * 4;           off = (off + 255) & ~(size_t)255;
    float* e_nh = (float*)(ws + off);
    off += (size_t)H_DIM * N_V * 4;

    int prep_threads = WTOT + XCH + WACT;
    prep<<<(prep_threads + 255) / 256, 256, 0, stream>>>(
        Wvc, Wvn_int, Wvn_nh, vertices, a, Wt, Xb, wab);

    dim3 grid_g((N_V + 63) / 64, 9);
    gemm_kernel<<<grid_g, 256, 0, stream>>>(Xb, Wt, wab, out, Vint, Vnh,
                                            e_center, e_int, e_nh);

    for (int h = 0; h < H_DIM; ++h) {
        attn_head_kernel<<<(N_V + 3) / 4, 256, 0, stream>>>(
            nh_indices, int_indices, nh_edges, int_edges,
            bv + h * 128,
            Vint + (size_t)h * N_V * 128,
            Vnh  + (size_t)h * N_V * 128,
            e_center + (size_t)h * N_V,
            e_int    + (size_t)h * N_V,
            e_nh     + (size_t)h * N_V,
            out, h * 128);
    }
}